// Round 10
// baseline (186.520 us; speedup 1.0000x reference)
//
#include <hip/hip_runtime.h>
#include <hip/hip_bf16.h>

// loss = mean_n( logsumexp([pos_n, (online@queue)_n]/t) - pos_n/t )   (fwd: alpha mix = identity)
// v10: 32x32x16 MFMA, BN=64 stripes (32 KB LDS), 64x64 wave tile via 2x2 of 32x32,
//      acc 64 regs + half-size fragments -> full A/B ping-pong at 3-4 waves/SIMD.
//      1024 blocks. Base-2 softmax; 3 graph nodes.

#define NROWS 1024
#define DDIM  256
#define KQ    65536
#define BN    64
#define NPART 1024
#define LN2_F 0.69314718055994531f

typedef short  short8   __attribute__((ext_vector_type(8)));
typedef float  floatx4  __attribute__((ext_vector_type(4)));
typedef float  floatx16 __attribute__((ext_vector_type(16)));

__device__ __forceinline__ unsigned short f2bf(float f) {
    unsigned int u = __float_as_uint(f);
    u += 0x7FFFu + ((u >> 16) & 1u);   // RNE
    return (unsigned short)(u >> 16);
}

#define DPPMOV(x, ctrl) \
    __uint_as_float(__builtin_amdgcn_mov_dpp(__float_as_uint(x), (ctrl), 0xF, 0xF, true))

__device__ __forceinline__ float dpp16_max(float x) {
    x = fmaxf(x, DPPMOV(x, 0xB1));    // quad xor1
    x = fmaxf(x, DPPMOV(x, 0x4E));    // quad xor2
    x = fmaxf(x, DPPMOV(x, 0x141));   // row_half_mirror (~xor4 after 1,2)
    x = fmaxf(x, DPPMOV(x, 0x140));   // row_mirror (~xor8)
    return x;
}
__device__ __forceinline__ float dpp16_sum(float x) {
    x += DPPMOV(x, 0xB1);
    x += DPPMOV(x, 0x4E);
    x += DPPMOV(x, 0x141);
    x += DPPMOV(x, 0x140);
    return x;
}

// ---- A conversion: bf16(A/(t*ln2)); also zeroes the output accumulator ----
__global__ __launch_bounds__(256)
void conv_a(const float* __restrict__ A, const float* __restrict__ temp,
            unsigned short* __restrict__ Ab, float* __restrict__ out)
{
    if (blockIdx.x == 0 && threadIdx.x == 0) out[0] = 0.0f;
    const float s = 1.0f / (temp[0] * LN2_F);
    const int i = blockIdx.x * 256 + threadIdx.x;       // 65536 threads, one float4 each
    const floatx4 v = ((const floatx4*)A)[i];
    ushort4 w;
    w.x = f2bf(v.x * s); w.y = f2bf(v.y * s);
    w.z = f2bf(v.z * s); w.w = f2bf(v.w * s);
    ((ushort4*)Ab)[i] = w;
}

// ---- fused GEMM + online-softmax partials. 1024 blocks x 256 thr; block = one 64-col stripe ----
__global__ __launch_bounds__(256, 3)
void gemm_softmax(const unsigned short* __restrict__ Ab,   // [1024][256] bf16, pre-scaled
                  const float* __restrict__ Q,             // [256][65536] fp32
                  float2* __restrict__ partials)           // [NPART][1024]  (part-major)
{
    __shared__ __align__(16) unsigned short Bl[BN * DDIM];   // [n][k] bf16, 32 KB, swizzled

    const int tid  = threadIdx.x;
    const int lane = tid & 63;
    const int wave = tid >> 6;          // 0..3 (row bands)
    const int l31  = lane & 31;
    const int l15  = lane & 15;
    const int half = lane >> 5;         // 0..1
    const int nb   = blockIdx.x;        // 0..1023
    const int nbase = nb * BN;

    // ---- stage B once: Q[k][nbase..+63] fp32 -> Bl[n][k] bf16 (register transpose) ----
    #pragma unroll
    for (int iter = 0; iter < 2; ++iter) {
        const int t2 = iter * 256 + tid;    // 512 tasks
        const int ny = t2 & 15;             // n-quad (4 cols)
        const int ko = t2 >> 4;             // k-octet (8 rows), 0..31
        floatx4 v[8];
        #pragma unroll
        for (int j = 0; j < 8; ++j)
            v[j] = __builtin_nontemporal_load(
                       (const floatx4*)(Q + (size_t)(ko * 8 + j) * KQ + nbase + ny * 4));
        #pragma unroll
        for (int i2 = 0; i2 < 4; ++i2) {
            const int n = ny * 4 + i2;
            const int phys = ko ^ (n & 15);      // 16B-chunk XOR swizzle (32 chunks/row)
            short8 w;
            #pragma unroll
            for (int j = 0; j < 8; ++j)
                w[j] = (short)f2bf(v[j][i2]);
            *(short8*)&Bl[n * DDIM + phys * 8] = w;
        }
    }
    __syncthreads();   // the ONLY barrier

    // B LDS byte bases per col-tile tj; per s add swizzled chunk offset.
    const int nA = l31 * 512;              // tj=0 row base (bytes)
    const int nB = (32 + l31) * 512;       // tj=1

    #pragma unroll 1
    for (int g = 0; g < 4; ++g) {
        const int rowbase = g * 256 + wave * 64;
        // A frag (32x32x16): A[m = lane&31][k = half*8 + j], advance k by s*16
        const unsigned short* apb = Ab + (size_t)(rowbase + l31) * DDIM + half * 8;

        floatx16 acc[2][2] = {};
        short8 afA[2], afB[2], bfA[2], bfB[2];

        // prologue: s=0
        afA[0] = *(const short8*)(apb);
        afA[1] = *(const short8*)(apb + 32 * DDIM);
        {
            const int off = ((half ^ l15) * 16);           // kc = 2*0 + half
            bfA[0] = *(const short8*)((const char*)Bl + nA + off);
            bfA[1] = *(const short8*)((const char*)Bl + nB + off);
        }

        #pragma unroll 1
        for (int sp = 0; sp < 8; ++sp) {
            const int s1 = 2 * sp + 1;
            afB[0] = *(const short8*)(apb + s1 * 16);
            afB[1] = *(const short8*)(apb + 32 * DDIM + s1 * 16);
            {
                const int off = (((2 * s1 + half) ^ l15) * 16);
                bfB[0] = *(const short8*)((const char*)Bl + nA + off);
                bfB[1] = *(const short8*)((const char*)Bl + nB + off);
            }
            acc[0][0] = __builtin_amdgcn_mfma_f32_32x32x16_bf16(afA[0], bfA[0], acc[0][0], 0, 0, 0);
            acc[0][1] = __builtin_amdgcn_mfma_f32_32x32x16_bf16(afA[0], bfA[1], acc[0][1], 0, 0, 0);
            acc[1][0] = __builtin_amdgcn_mfma_f32_32x32x16_bf16(afA[1], bfA[0], acc[1][0], 0, 0, 0);
            acc[1][1] = __builtin_amdgcn_mfma_f32_32x32x16_bf16(afA[1], bfA[1], acc[1][1], 0, 0, 0);

            const int s2 = (2 * sp + 2) & 15;   // sp==7 loads are dead; cheap
            afA[0] = *(const short8*)(apb + s2 * 16);
            afA[1] = *(const short8*)(apb + 32 * DDIM + s2 * 16);
            {
                const int off = (((2 * s2 + half) ^ l15) * 16);
                bfA[0] = *(const short8*)((const char*)Bl + nA + off);
                bfA[1] = *(const short8*)((const char*)Bl + nB + off);
            }
            acc[0][0] = __builtin_amdgcn_mfma_f32_32x32x16_bf16(afB[0], bfB[0], acc[0][0], 0, 0, 0);
            acc[0][1] = __builtin_amdgcn_mfma_f32_32x32x16_bf16(afB[0], bfB[1], acc[0][1], 0, 0, 0);
            acc[1][0] = __builtin_amdgcn_mfma_f32_32x32x16_bf16(afB[1], bfB[0], acc[1][0], 0, 0, 0);
            acc[1][1] = __builtin_amdgcn_mfma_f32_32x32x16_bf16(afB[1], bfB[1], acc[1][1], 0, 0, 0);
        }

        // epilogue: base-2 logits. 32x32 C layout (verified m74/m101):
        //   col = lane&31 (+tj*32), row = (reg&3) + 8*(reg>>2) + 4*half (+ti*32)
        #pragma unroll
        for (int ti = 0; ti < 2; ++ti) {
            float2 vals[16];
            #pragma unroll
            for (int reg = 0; reg < 16; ++reg) {
                float mx = fmaxf(acc[ti][0][reg], acc[ti][1][reg]);
                mx = dpp16_max(mx);
                mx = fmaxf(mx, __shfl_xor(mx, 16, 64));
                float s2 = __builtin_amdgcn_exp2f(acc[ti][0][reg] - mx)
                         + __builtin_amdgcn_exp2f(acc[ti][1][reg] - mx);
                s2 = dpp16_sum(s2);
                s2 += __shfl_xor(s2, 16, 64);
                vals[reg] = make_float2(mx, s2);
            }
            if (l31 == 0) {
                // lane 0 writes half=0 rows, lane 32 writes half=1 rows
                const int rb0 = rowbase + ti * 32 + 4 * half;
                float2* dst = partials + (size_t)nb * NROWS + rb0;
                #pragma unroll
                for (int q = 0; q < 4; ++q) {
                    floatx4 w0 = {vals[q*4+0].x, vals[q*4+0].y, vals[q*4+1].x, vals[q*4+1].y};
                    floatx4 w1 = {vals[q*4+2].x, vals[q*4+2].y, vals[q*4+3].x, vals[q*4+3].y};
                    __builtin_nontemporal_store(w0, (floatx4*)(dst + q * 8));
                    __builtin_nontemporal_store(w1, (floatx4*)(dst + q * 8 + 2));
                }
            }
        }
    }
}

// ---- combine partials per row + positive logit (inline) + atomic mean ----
// Grid: 64 blocks x 256 threads. Block owns 16 rows; 16 part-groups of 64 parts.
__global__ __launch_bounds__(256)
void finalize_rows(const float2* __restrict__ partials,   // [NPART][1024]
                   const float* __restrict__ online,
                   const float* __restrict__ mom,
                   const float* __restrict__ temp,
                   float* __restrict__ out)
{
    const int t = threadIdx.x;
    __shared__ float2 sm[16][17];
    __shared__ float sm_pos[16];

    // phase 1: positive-pair logit, 16 threads per row
    {
        const float s = 1.0f / (temp[0] * LN2_F);
        const int r2 = t >> 4, c2 = t & 15;
        const float* po = online + (size_t)(blockIdx.x * 16 + r2) * DDIM + c2 * 16;
        const float* pm = mom    + (size_t)(blockIdx.x * 16 + r2) * DDIM + c2 * 16;
        float d = 0.f;
        #pragma unroll
        for (int w = 0; w < 4; ++w) {
            const floatx4 a = *(const floatx4*)(po + w * 4);
            const floatx4 b = *(const floatx4*)(pm + w * 4);
            d += a.x * b.x + a.y * b.y + a.z * b.z + a.w * b.w;
        }
        d = dpp16_sum(d);
        if (c2 == 0) sm_pos[r2] = d * s;    // base-2-domain positive logit
    }

    // phase 2: combine negative partials
    const int rl  = t & 15;
    const int grp = t >> 4;
    const int row = blockIdx.x * 16 + rl;

    float M = -3.0e38f, S = 0.f;
    #pragma unroll 1
    for (int pb = 0; pb < 64; pb += 8) {
        float2 v[8];
        #pragma unroll
        for (int j = 0; j < 8; ++j)
            v[j] = partials[(size_t)(grp * 64 + pb + j) * NROWS + row];
        #pragma unroll
        for (int j = 0; j < 8; ++j) {
            const float M2 = fmaxf(M, v[j].x);
            S = S * __builtin_amdgcn_exp2f(M - M2) + v[j].y * __builtin_amdgcn_exp2f(v[j].x - M2);
            M = M2;
        }
    }
    sm[grp][rl] = make_float2(M, S);
    __syncthreads();

    if (t < 64) {
        float val = 0.f;
        if (t < 16) {
            float Mm = -3.0e38f, Ss = 0.f;
            #pragma unroll
            for (int g2 = 0; g2 < 16; ++g2) {
                const float2 v = sm[g2][t];
                const float M2 = fmaxf(Mm, v.x);
                Ss = Ss * __builtin_amdgcn_exp2f(Mm - M2) + v.y * __builtin_amdgcn_exp2f(v.x - M2);
                Mm = M2;
            }
            const float p  = sm_pos[t];
            const float M2 = fmaxf(Mm, p);
            const float L  = Ss * __builtin_amdgcn_exp2f(Mm - M2) + __builtin_amdgcn_exp2f(p - M2);
            val = (M2 + __builtin_amdgcn_logf(L) - p) * LN2_F;   // back to natural log
        }
        val += __shfl_xor(val, 1, 64);
        val += __shfl_xor(val, 2, 64);
        val += __shfl_xor(val, 4, 64);
        val += __shfl_xor(val, 8, 64);
        val += __shfl_xor(val, 16, 64);
        val += __shfl_xor(val, 32, 64);
        if (t == 0) atomicAdd(out, val * (1.0f / (float)NROWS));
    }
}

extern "C" void kernel_launch(void* const* d_in, const int* in_sizes, int n_in,
                              void* d_out, int out_size, void* d_ws, size_t ws_size,
                              hipStream_t stream)
{
    const float* online = (const float*)d_in[0];   // [1024][256]
    const float* mom    = (const float*)d_in[1];   // [1024][256]
    const float* queue  = (const float*)d_in[2];   // [256][65536]
    const float* temp   = (const float*)d_in[3];   // [1]
    float* out = (float*)d_out;

    // ws: Ab bf16 [1024][256] (512 KB) | partials float2 [1024][1024] (8 MB)
    char* ws = (char*)d_ws;
    unsigned short* Ab = (unsigned short*)ws;
    float2* partials   = (float2*)(ws + 524288);

    conv_a<<<256, 256, 0, stream>>>(online, temp, Ab, out);
    gemm_softmax<<<KQ / BN, 256, 0, stream>>>(Ab, queue, partials);
    finalize_rows<<<64, 256, 0, stream>>>(partials, online, mom, temp, out);
}

// Round 11
// 176.838 us; speedup vs baseline: 1.0548x; 1.0548x over previous
//
#include <hip/hip_runtime.h>
#include <hip/hip_bf16.h>
#include <hip/hip_fp8.h>

// loss = mean_n( logsumexp([pos_n, (online@queue)_n]/t) - pos_n/t )   (fwd: alpha mix = identity)
// v11: fp8-e4m3 GEMM (16x16x32_fp8_fp8, non-scaled = bf16 rate but half-size fragments):
//      BN=64 stripes -> 16 KB LDS -> 4 blocks/CU, 4 waves/SIMD, full A/B ping-pong in 128 regs.
//      B ds_read_b64 halves LDS-pipe pressure (v9's real wall). pos-term stays fp32-exact.

#define NROWS 1024
#define DDIM  256
#define KQ    65536
#define BN    64
#define NPART 1024
#define LN2_F 0.69314718055994531f

typedef float floatx4 __attribute__((ext_vector_type(4)));

__device__ __forceinline__ unsigned char f2e4(float f) {
    __hip_fp8_e4m3 t(f);                 // OCP e4m3fn, RNE (HW cvt on gfx950)
    return (unsigned char)t.__x;
}

#define DPPMOV(x, ctrl) \
    __uint_as_float(__builtin_amdgcn_mov_dpp(__float_as_uint(x), (ctrl), 0xF, 0xF, true))

__device__ __forceinline__ float dpp16_max(float x) {
    x = fmaxf(x, DPPMOV(x, 0xB1));    // quad xor1
    x = fmaxf(x, DPPMOV(x, 0x4E));    // quad xor2
    x = fmaxf(x, DPPMOV(x, 0x141));   // row_half_mirror
    x = fmaxf(x, DPPMOV(x, 0x140));   // row_mirror
    return x;
}
__device__ __forceinline__ float dpp16_sum(float x) {
    x += DPPMOV(x, 0xB1);
    x += DPPMOV(x, 0x4E);
    x += DPPMOV(x, 0x141);
    x += DPPMOV(x, 0x140);
    return x;
}

// ---- A conversion: fp8(A/(t*ln2)); also zeroes the output accumulator ----
__global__ __launch_bounds__(256)
void conv_a(const float* __restrict__ A, const float* __restrict__ temp,
            unsigned char* __restrict__ Ab, float* __restrict__ out)
{
    if (blockIdx.x == 0 && threadIdx.x == 0) out[0] = 0.0f;
    const float s = 1.0f / (temp[0] * LN2_F);
    const int i = blockIdx.x * 256 + threadIdx.x;       // 65536 threads, one float4 each
    const floatx4 v = ((const floatx4*)A)[i];
    unsigned int w = (unsigned int)f2e4(v.x * s)
                   | ((unsigned int)f2e4(v.y * s) << 8)
                   | ((unsigned int)f2e4(v.z * s) << 16)
                   | ((unsigned int)f2e4(v.w * s) << 24);
    ((unsigned int*)Ab)[i] = w;
}

// ---- fused GEMM + online-softmax partials. 1024 blocks x 256 thr; block = one 64-col stripe ----
__global__ __launch_bounds__(256, 4)
void gemm_softmax(const unsigned char* __restrict__ Ab,   // [1024][256] fp8, pre-scaled
                  const float* __restrict__ Q,            // [256][65536] fp32
                  float2* __restrict__ partials)          // [NPART][1024]  (part-major)
{
    __shared__ __align__(16) unsigned char Bl[BN * DDIM]; // [n][k] fp8, 16 KB, 8B-chunk swizzle

    const int tid  = threadIdx.x;
    const int lane = tid & 63;
    const int wave = tid >> 6;          // 0..3 (row bands)
    const int l15  = lane & 15;
    const int quad = lane >> 4;
    const int nb   = blockIdx.x;        // 0..1023
    const int nbase = nb * BN;

    // ---- stage B once: Q[k][nbase..+63] fp32 -> Bl[n][k] fp8 (register transpose) ----
    #pragma unroll
    for (int iter = 0; iter < 2; ++iter) {
        const int t2 = iter * 256 + tid;    // 512 tasks
        const int ny = t2 & 15;             // n-quad (4 cols)
        const int ko = t2 >> 4;             // k-octet (8 rows), 0..31
        floatx4 v[8];
        #pragma unroll
        for (int j = 0; j < 8; ++j)
            v[j] = __builtin_nontemporal_load(
                       (const floatx4*)(Q + (size_t)(ko * 8 + j) * KQ + nbase + ny * 4));
        #pragma unroll
        for (int i2 = 0; i2 < 4; ++i2) {
            const int n = ny * 4 + i2;
            const int phys = (ko & 16) | ((ko ^ n) & 15);   // 8B-chunk swizzle, read-compatible
            unsigned long w = 0;
            #pragma unroll
            for (int j = 0; j < 8; ++j)
                w |= (unsigned long)f2e4(v[j][i2]) << (8 * j);
            *(unsigned long*)&Bl[n * DDIM + phys * 8] = w;
        }
    }
    __syncthreads();   // the ONLY barrier

    #pragma unroll 1
    for (int g = 0; g < 4; ++g) {
        const int rowbase = g * 256 + wave * 64;
        const unsigned char* apb = Ab + (size_t)(rowbase + l15) * DDIM + quad * 8;

        floatx4 acc[4][4] = {};
        long afA[4], afB[4], bfA[4], bfB[4];

        // prologue: s=0 (chunk c = quad)
        #pragma unroll
        for (int i = 0; i < 4; ++i)
            afA[i] = *(const long*)(apb + i * 16 * DDIM);
        {
            const int phys = (quad & 16) | ((quad ^ l15) & 15);
            #pragma unroll
            for (int j = 0; j < 4; ++j)
                bfA[j] = *(const long*)&Bl[(j * 16 + l15) * DDIM + phys * 8];
        }

        #pragma unroll 1
        for (int sp = 0; sp < 4; ++sp) {
            const int s1 = 2 * sp + 1;
            #pragma unroll
            for (int i = 0; i < 4; ++i)
                afB[i] = *(const long*)(apb + i * 16 * DDIM + s1 * 32);
            {
                const int c = 4 * s1 + quad;
                const int phys = (c & 16) | ((c ^ l15) & 15);
                #pragma unroll
                for (int j = 0; j < 4; ++j)
                    bfB[j] = *(const long*)&Bl[(j * 16 + l15) * DDIM + phys * 8];
            }
            #pragma unroll
            for (int i = 0; i < 4; ++i)
                #pragma unroll
                for (int j = 0; j < 4; ++j)
                    acc[i][j] = __builtin_amdgcn_mfma_f32_16x16x32_fp8_fp8(afA[i], bfA[j], acc[i][j], 0, 0, 0);

            const int s2 = (2 * sp + 2) & 7;   // sp==3 loads are dead; cheap
            #pragma unroll
            for (int i = 0; i < 4; ++i)
                afA[i] = *(const long*)(apb + i * 16 * DDIM + s2 * 32);
            {
                const int c = 4 * s2 + quad;
                const int phys = (c & 16) | ((c ^ l15) & 15);
                #pragma unroll
                for (int j = 0; j < 4; ++j)
                    bfA[j] = *(const long*)&Bl[(j * 16 + l15) * DDIM + phys * 8];
            }
            #pragma unroll
            for (int i = 0; i < 4; ++i)
                #pragma unroll
                for (int j = 0; j < 4; ++j)
                    acc[i][j] = __builtin_amdgcn_mfma_f32_16x16x32_fp8_fp8(afB[i], bfB[j], acc[i][j], 0, 0, 0);
        }

        // epilogue: base-2 logits. C layout: col(n)=lane&15, row(m)=quad*4+reg (dtype-independent).
        #pragma unroll
        for (int i = 0; i < 4; ++i) {
            float2 tmp[4];
            #pragma unroll
            for (int r = 0; r < 4; ++r) {
                float mx = fmaxf(fmaxf(acc[i][0][r], acc[i][1][r]),
                                 fmaxf(acc[i][2][r], acc[i][3][r]));
                mx = dpp16_max(mx);
                float s2 = 0.f;
                #pragma unroll
                for (int j = 0; j < 4; ++j)
                    s2 += __builtin_amdgcn_exp2f(acc[i][j][r] - mx);
                s2 = dpp16_sum(s2);
                tmp[r] = make_float2(mx, s2);
            }
            if (l15 == 0) {
                // 4 quad-leader lanes cover 128 contiguous bytes
                const int row = rowbase + i * 16 + quad * 4;
                floatx4* dst = (floatx4*)(partials + (size_t)nb * NROWS + row);
                floatx4 w0 = {tmp[0].x, tmp[0].y, tmp[1].x, tmp[1].y};
                floatx4 w1 = {tmp[2].x, tmp[2].y, tmp[3].x, tmp[3].y};
                __builtin_nontemporal_store(w0, dst);
                __builtin_nontemporal_store(w1, dst + 1);
            }
        }
    }
}

// ---- combine partials per row + positive logit (inline, fp32-exact) + atomic mean ----
// Grid: 64 blocks x 256 threads. Block owns 16 rows; 16 part-groups of 64 parts.
__global__ __launch_bounds__(256)
void finalize_rows(const float2* __restrict__ partials,   // [NPART][1024]
                   const float* __restrict__ online,
                   const float* __restrict__ mom,
                   const float* __restrict__ temp,
                   float* __restrict__ out)
{
    const int t = threadIdx.x;
    __shared__ float2 sm[16][17];
    __shared__ float sm_pos[16];

    // phase 1: positive-pair logit, 16 threads per row
    {
        const float s = 1.0f / (temp[0] * LN2_F);
        const int r2 = t >> 4, c2 = t & 15;
        const float* po = online + (size_t)(blockIdx.x * 16 + r2) * DDIM + c2 * 16;
        const float* pm = mom    + (size_t)(blockIdx.x * 16 + r2) * DDIM + c2 * 16;
        float d = 0.f;
        #pragma unroll
        for (int w = 0; w < 4; ++w) {
            const floatx4 a = *(const floatx4*)(po + w * 4);
            const floatx4 b = *(const floatx4*)(pm + w * 4);
            d += a.x * b.x + a.y * b.y + a.z * b.z + a.w * b.w;
        }
        d = dpp16_sum(d);
        if (c2 == 0) sm_pos[r2] = d * s;    // base-2-domain positive logit
    }

    // phase 2: combine negative partials
    const int rl  = t & 15;
    const int grp = t >> 4;
    const int row = blockIdx.x * 16 + rl;

    float M = -3.0e38f, S = 0.f;
    #pragma unroll 1
    for (int pb = 0; pb < 64; pb += 8) {
        float2 v[8];
        #pragma unroll
        for (int j = 0; j < 8; ++j)
            v[j] = partials[(size_t)(grp * 64 + pb + j) * NROWS + row];
        #pragma unroll
        for (int j = 0; j < 8; ++j) {
            const float M2 = fmaxf(M, v[j].x);
            S = S * __builtin_amdgcn_exp2f(M - M2) + v[j].y * __builtin_amdgcn_exp2f(v[j].x - M2);
            M = M2;
        }
    }
    sm[grp][rl] = make_float2(M, S);
    __syncthreads();

    if (t < 64) {
        float val = 0.f;
        if (t < 16) {
            float Mm = -3.0e38f, Ss = 0.f;
            #pragma unroll
            for (int g2 = 0; g2 < 16; ++g2) {
                const float2 v = sm[g2][t];
                const float M2 = fmaxf(Mm, v.x);
                Ss = Ss * __builtin_amdgcn_exp2f(Mm - M2) + v.y * __builtin_amdgcn_exp2f(v.x - M2);
                Mm = M2;
            }
            const float p  = sm_pos[t];
            const float M2 = fmaxf(Mm, p);
            const float L  = Ss * __builtin_amdgcn_exp2f(Mm - M2) + __builtin_amdgcn_exp2f(p - M2);
            val = (M2 + __builtin_amdgcn_logf(L) - p) * LN2_F;   // back to natural log
        }
        val += __shfl_xor(val, 1, 64);
        val += __shfl_xor(val, 2, 64);
        val += __shfl_xor(val, 4, 64);
        val += __shfl_xor(val, 8, 64);
        val += __shfl_xor(val, 16, 64);
        val += __shfl_xor(val, 32, 64);
        if (t == 0) atomicAdd(out, val * (1.0f / (float)NROWS));
    }
}

extern "C" void kernel_launch(void* const* d_in, const int* in_sizes, int n_in,
                              void* d_out, int out_size, void* d_ws, size_t ws_size,
                              hipStream_t stream)
{
    const float* online = (const float*)d_in[0];   // [1024][256]
    const float* mom    = (const float*)d_in[1];   // [1024][256]
    const float* queue  = (const float*)d_in[2];   // [256][65536]
    const float* temp   = (const float*)d_in[3];   // [1]
    float* out = (float*)d_out;

    // ws: Ab fp8 [1024][256] (256 KB) | partials float2 [1024][1024] (8 MB)
    char* ws = (char*)d_ws;
    unsigned char* Ab = (unsigned char*)ws;
    float2* partials  = (float2*)(ws + 262144);

    conv_a<<<256, 256, 0, stream>>>(online, temp, Ab, out);
    gemm_softmax<<<KQ / BN, 256, 0, stream>>>(Ab, queue, partials);
    finalize_rows<<<64, 256, 0, stream>>>(partials, online, mom, temp, out);
}